// Round 5
// baseline (1513.471 us; speedup 1.0000x reference)
//
#include <hip/hip_runtime.h>
#include <cstdint>
#include <cstddef>

// ---------------------------------------------------------------------------
// GCN 2-layer, N=100k nodes, E=1.6M edges, F=64, fp32 in/out.
//
//   dis[n] = rsqrt(in_deg[n]+1)         (self-loop folded in analytically)
//   g   = bf16( (X @ W1) * dis[row] )   GEMM via MFMA, split-bf16 x3
//   h   = relu( dis * (agg g) + b1 )    BUCKET-DIRECT agg in LDS (R5)
//   g'  = bf16( (h @ W2) * dis )        fused MFMA epilogue in aggb1
//   out = dis * (agg g') + b2           bucket-direct agg + epilogue
//
// R5 restructure: CSR is gone. bscatter still bins edges into padded
// per-bucket windows (256 nodes/bucket, CAP 5376 = mean 4096 + 20 sigma),
// but aggregation now happens per-bucket: each 1024-thread block owns one
// bucket's fp32 accumulator in LDS (256 x stride-67 = 67 KB, odd stride ->
// ~2-way bank conflicts = free), streams its window coalesced, gathers
// g16[src] rows (8 lanes/row) and ds_add_f32's into LDS. Deletes k_build,
// col (12.8 MB traffic), rp/dega, one gather dependency level, and the
// per-wave max-deg padding waste. launch_bounds(1024,8) targets VGPR<=64
// -> 2 blocks/CU = 32 waves/CU (vs measured 33% occupancy of CSR agg).
// R3 lesson kept: MFMA epilogue fusion of h@W2 (bit-identical tile math).
// R2/R4 lessons kept: no manual gather pipelining; CSR-side tweaks dead end.
// ---------------------------------------------------------------------------

#define BK_SHIFT 8                 // 256 nodes per bucket
#define BK_NODES 256
#define EPB 8192                   // edges per scatter block (long runs)
#define CAP 5376                   // padded bucket capacity (mean 4096 + 20s)
#define NBMAX 512                  // max buckets (N<=131072 -> NB<=512)
#define ACCW 67                    // LDS accumulator row stride (odd)

typedef short bf16x8 __attribute__((ext_vector_type(8)));
typedef float f32x4  __attribute__((ext_vector_type(4)));

static __device__ __forceinline__ unsigned short f2b(float f) {
    unsigned x = __float_as_uint(f);
    unsigned r = (x + 0x7FFFu + ((x >> 16) & 1u)) >> 16;   // RNE
    return (unsigned short)r;
}
static __device__ __forceinline__ float blo(unsigned u) {
    return __uint_as_float(u << 16);
}
static __device__ __forceinline__ float bhi(unsigned u) {
    return __uint_as_float(u & 0xFFFF0000u);
}
static __device__ __forceinline__ void splitbf(float x, short& hi, short& lo) {
    unsigned short h = f2b(x);
    hi = (short)h;
    float r = x - __uint_as_float((unsigned)h << 16);
    lo = (short)f2b(r);
}

// ---- init: gcursor[b] = b*CAP --------------------------------------------
__global__ void k_init(int* __restrict__ gcursor, int NB) {
    int t = threadIdx.x;
    if (t < NB) gcursor[t] = t * CAP;
}

// ---- scatter edges into padded bucket windows, packed uint32 --------------
// pack = src (17 bits) | dst_local (8 bits) << 17   (N <= 131072)
// Assumes E % 4 == 0 (E=1.6M). 8192 edges/block; loads batched for ILP.
__global__ void __launch_bounds__(256) k_bscatter(const int* __restrict__ src,
                                                  const int* __restrict__ dst,
                                                  int* __restrict__ gcursor,
                                                  unsigned* __restrict__ packed,
                                                  int E, int NB) {
    __shared__ int hist[NBMAX];
    __shared__ int base[NBMAX];
    int t = threadIdx.x;
    for (int i = t; i < NB; i += 256) hist[i] = 0;
    __syncthreads();
    int e0 = blockIdx.x * EPB;
    int e1 = min(e0 + EPB, E);
    // phase 1: block histogram (8 int4 loads batched, then atomics)
    int4 dv[8];
    int kd[8];
#pragma unroll
    for (int k = 0; k < 8; ++k) {
        int e = e0 + t * 4 + k * 1024;
        kd[k] = (e + 3 < e1) ? 1 : 0;
        if (kd[k]) dv[k] = *(const int4*)(dst + e);
    }
#pragma unroll
    for (int k = 0; k < 8; ++k) {
        if (kd[k]) {
            atomicAdd(&hist[dv[k].x >> BK_SHIFT], 1);
            atomicAdd(&hist[dv[k].y >> BK_SHIFT], 1);
            atomicAdd(&hist[dv[k].z >> BK_SHIFT], 1);
            atomicAdd(&hist[dv[k].w >> BK_SHIFT], 1);
        }
    }
    __syncthreads();
    // phase 2: reserve chunk in each bucket's padded window
    for (int i = t; i < NB; i += 256) {
        int c = hist[i];
        base[i] = c ? atomicAdd(&gcursor[i], c) : 0;
        hist[i] = 0;
    }
    __syncthreads();
    // phase 3: scatter (batched src loads; dst re-used from regs)
    int4 sv[8];
#pragma unroll
    for (int k = 0; k < 8; ++k) {
        int e = e0 + t * 4 + k * 1024;
        if (kd[k]) sv[k] = *(const int4*)(src + e);
    }
#pragma unroll
    for (int k = 0; k < 8; ++k) {
        if (kd[k]) {
            int b0 = dv[k].x >> BK_SHIFT;
            int p0 = base[b0] + atomicAdd(&hist[b0], 1);
            packed[p0] = (unsigned)sv[k].x | (((unsigned)dv[k].x & (BK_NODES - 1)) << 17);
            int b1 = dv[k].y >> BK_SHIFT;
            int p1 = base[b1] + atomicAdd(&hist[b1], 1);
            packed[p1] = (unsigned)sv[k].y | (((unsigned)dv[k].y & (BK_NODES - 1)) << 17);
            int b2 = dv[k].z >> BK_SHIFT;
            int p2 = base[b2] + atomicAdd(&hist[b2], 1);
            packed[p2] = (unsigned)sv[k].z | (((unsigned)dv[k].z & (BK_NODES - 1)) << 17);
            int b3 = dv[k].w >> BK_SHIFT;
            int p3 = base[b3] + atomicAdd(&hist[b3], 1);
            packed[p3] = (unsigned)sv[k].w | (((unsigned)dv[k].w & (BK_NODES - 1)) << 17);
        }
    }
}

// ---- per-bucket degree count -> dis only (no CSR build) -------------------
__global__ void __launch_bounds__(256) k_count(const unsigned* __restrict__ packed,
                                               const int* __restrict__ gcursor,
                                               float* __restrict__ dis, int N) {
    __shared__ int cnt[BK_NODES];
    int b = blockIdx.x;
    int t = threadIdx.x;
    cnt[t] = 0;
    __syncthreads();
    int e0 = b * CAP;
    int e1 = gcursor[b];
    for (int e = e0 + t; e < e1; e += 256) atomicAdd(&cnt[packed[e] >> 17], 1);
    __syncthreads();
    int node = (b << BK_SHIFT) + t;
    if (node < N) dis[node] = rsqrtf((float)(cnt[t] + 1));
}

// ---- GEMM via MFMA: g16[row] = bf16( (X[row] @ W) * dis[row] ) ------------
// Layouts (measured, learn_hip m89/m91/m120):
//   A[m=lane&15][k=quad*8+j]   B[k=quad*8+j][n=lane&15]
//   C: col=lane&15, row=quad*4+reg
__global__ void __launch_bounds__(256) k_gemm_mfma(const float* __restrict__ X,
                                                   const float* __restrict__ W,
                                                   const float* __restrict__ dis,
                                                   unsigned short* __restrict__ g16,
                                                   int n, int nstrips) {
    __shared__ float Ws[4096];     // 64x64 fp32 = 16 KB
    int t = threadIdx.x;
    {
        const float4* W4 = (const float4*)W;
        float4* S4 = (float4*)Ws;
#pragma unroll
        for (int i = 0; i < 4; ++i) S4[t + i * 256] = W4[t + i * 256];
    }
    __syncthreads();
    int wid  = t >> 6;
    int lane = t & 63;
    int quad = lane >> 4;
    int fl   = lane & 15;

    bf16x8 Bh[4][2], Bl[4][2];
#pragma unroll
    for (int tt = 0; tt < 4; ++tt)
#pragma unroll
        for (int c = 0; c < 2; ++c)
#pragma unroll
            for (int j = 0; j < 8; ++j) {
                float w = Ws[(c * 32 + quad * 8 + j) * 64 + tt * 16 + fl];
                short hi, lo;
                splitbf(w, hi, lo);
                Bh[tt][c][j] = hi;
                Bl[tt][c][j] = lo;
            }

    for (int s = blockIdx.x * 4 + wid; s < nstrips; s += gridDim.x * 4) {
        int row0 = s << 4;
        const float4* xp = (const float4*)(X + ((size_t)(row0 + fl) << 6));
        bf16x8 Ah[2], Al[2];
#pragma unroll
        for (int c = 0; c < 2; ++c) {
            float4 a = xp[c * 8 + quad * 2];
            float4 b = xp[c * 8 + quad * 2 + 1];
            float xs[8] = {a.x, a.y, a.z, a.w, b.x, b.y, b.z, b.w};
#pragma unroll
            for (int j = 0; j < 8; ++j) {
                short hi, lo;
                splitbf(xs[j], hi, lo);
                Ah[c][j] = hi;
                Al[c][j] = lo;
            }
        }
        f32x4 acc[4];
#pragma unroll
        for (int tt = 0; tt < 4; ++tt) acc[tt] = (f32x4){0.f, 0.f, 0.f, 0.f};
#pragma unroll
        for (int tt = 0; tt < 4; ++tt) {
#pragma unroll
            for (int c = 0; c < 2; ++c) {
                acc[tt] = __builtin_amdgcn_mfma_f32_16x16x32_bf16(Ah[c], Bh[tt][c], acc[tt], 0, 0, 0);
                acc[tt] = __builtin_amdgcn_mfma_f32_16x16x32_bf16(Al[c], Bh[tt][c], acc[tt], 0, 0, 0);
                acc[tt] = __builtin_amdgcn_mfma_f32_16x16x32_bf16(Ah[c], Bl[tt][c], acc[tt], 0, 0, 0);
            }
        }
        float4 dv = *(const float4*)(dis + row0 + quad * 4);
        float ds4[4] = {dv.x, dv.y, dv.z, dv.w};
#pragma unroll
        for (int tt = 0; tt < 4; ++tt) {
#pragma unroll
            for (int r = 0; r < 4; ++r) {
                int row = row0 + quad * 4 + r;
                float v = acc[tt][r] * ds4[r];
                g16[(size_t)row * 64 + tt * 16 + fl] = f2b(v);
            }
        }
    }
}

// ---- bucket agg L1: LDS accum -> h=relu(..) -> MFMA h@W2 -> g16b ----------
// 16 waves; gather: 8-lane groups, one g16 row per group per k-step,
// ds_add_f32 into acc (fire-and-forget). Epilogue 1: in-place h transform.
// Epilogue 2: wave wv computes rows [wv*16,wv*16+16) x 64 of h@W2 via MFMA
// (A from LDS h, B from global W2, same split-bf16x3 order as k_gemm_mfma).
__global__ void __launch_bounds__(1024, 8) k_aggb1(const unsigned short* __restrict__ g16,
                                                   const unsigned* __restrict__ packed,
                                                   const int* __restrict__ gcursor,
                                                   const float* __restrict__ dis,
                                                   const float* __restrict__ bias,
                                                   const float* __restrict__ W2,
                                                   unsigned short* __restrict__ g16b,
                                                   int N) {
    __shared__ float acc[BK_NODES * ACCW];     // 67 KB
    int t = threadIdx.x;
    int b = blockIdx.x;
    int node0 = b << BK_SHIFT;
    for (int i = t; i < BK_NODES * ACCW; i += 1024) acc[i] = 0.f;
    __syncthreads();

    int e0 = b * CAP;
    int count = gcursor[b] - e0;
    int lane = t & 63;
    int wv = t >> 6;                  // 0..15
    int sub = lane >> 3;
    int fl = lane & 7;
    for (int base = wv << 6; base < count; base += 1024) {
        int idx = base + lane;
        unsigned pe = (idx < count) ? packed[e0 + idx] : 0xFFFFFFFFu;
#pragma unroll
        for (int k = 0; k < 8; ++k) {
            unsigned p = __shfl(pe, k * 8 + sub);
            if (p != 0xFFFFFFFFu) {
                int srcn = (int)(p & 0x1FFFFu);
                int dl = (int)(p >> 17);
                uint4 u = *((const uint4*)(g16 + ((size_t)srcn << 6)) + fl);
                float* ap = &acc[dl * ACCW + fl * 8];
                atomicAdd(ap + 0, blo(u.x)); atomicAdd(ap + 1, bhi(u.x));
                atomicAdd(ap + 2, blo(u.y)); atomicAdd(ap + 3, bhi(u.y));
                atomicAdd(ap + 4, blo(u.z)); atomicAdd(ap + 5, bhi(u.z));
                atomicAdd(ap + 6, blo(u.w)); atomicAdd(ap + 7, bhi(u.w));
            }
        }
    }
    __syncthreads();

    // transform in place: acc -> h = relu(dis*(acc+self)+b1)
    {
        int row = t >> 2;              // 0..255
        int fg = (t & 3) << 4;         // 0,16,32,48
        int node = node0 + row;
        float* ap = &acc[row * ACCW + fg];
        if (node < N) {
            float s = dis[node];
            const uint4* sp = (const uint4*)(g16 + ((size_t)node << 6)) + ((t & 3) << 1);
            uint4 u0 = sp[0], u1 = sp[1];
            float sv[16];
            sv[0] = blo(u0.x); sv[1] = bhi(u0.x); sv[2] = blo(u0.y); sv[3] = bhi(u0.y);
            sv[4] = blo(u0.z); sv[5] = bhi(u0.z); sv[6] = blo(u0.w); sv[7] = bhi(u0.w);
            sv[8] = blo(u1.x); sv[9] = bhi(u1.x); sv[10] = blo(u1.y); sv[11] = bhi(u1.y);
            sv[12] = blo(u1.z); sv[13] = bhi(u1.z); sv[14] = blo(u1.w); sv[15] = bhi(u1.w);
#pragma unroll
            for (int j = 0; j < 16; ++j)
                ap[j] = fmaxf(fmaf(s, ap[j] + sv[j], bias[fg + j]), 0.f);
        } else {
#pragma unroll
            for (int j = 0; j < 16; ++j) ap[j] = 0.f;
        }
    }
    __syncthreads();

    // MFMA epilogue: rows [wv*16, wv*16+16) of (h @ W2) * dis -> bf16
    {
        int quad = lane >> 4;
        int fq = lane & 15;
        const float* hrow = &acc[((wv << 4) + fq) * ACCW];
        bf16x8 Ah[2], Al[2];
#pragma unroll
        for (int kc = 0; kc < 2; ++kc)
#pragma unroll
            for (int j = 0; j < 8; ++j) {
                short hi, lo;
                splitbf(hrow[kc * 32 + quad * 8 + j], hi, lo);
                Ah[kc][j] = hi;
                Al[kc][j] = lo;
            }
        int row0 = node0 + (wv << 4) + (quad << 2);
        float d4[4];
#pragma unroll
        for (int r = 0; r < 4; ++r) {
            int rr = row0 + r;
            d4[r] = (rr < N) ? dis[rr] : 0.f;
        }
#pragma unroll
        for (int tt = 0; tt < 4; ++tt) {
            bf16x8 Bh[2], Bl[2];
#pragma unroll
            for (int kc = 0; kc < 2; ++kc)
#pragma unroll
                for (int j = 0; j < 8; ++j) {
                    short hi, lo;
                    splitbf(W2[(kc * 32 + quad * 8 + j) * 64 + tt * 16 + fq], hi, lo);
                    Bh[kc][j] = hi;
                    Bl[kc][j] = lo;
                }
            f32x4 a = (f32x4){0.f, 0.f, 0.f, 0.f};
#pragma unroll
            for (int kc = 0; kc < 2; ++kc) {
                a = __builtin_amdgcn_mfma_f32_16x16x32_bf16(Ah[kc], Bh[kc], a, 0, 0, 0);
                a = __builtin_amdgcn_mfma_f32_16x16x32_bf16(Al[kc], Bh[kc], a, 0, 0, 0);
                a = __builtin_amdgcn_mfma_f32_16x16x32_bf16(Ah[kc], Bl[kc], a, 0, 0, 0);
            }
#pragma unroll
            for (int r = 0; r < 4; ++r) {
                int row = row0 + r;
                if (row < N)
                    g16b[(size_t)row * 64 + tt * 16 + fq] = f2b(a[r] * d4[r]);
            }
        }
    }
}

// ---- bucket agg L2: LDS accum -> out = dis*(acc+self)+b2 (fp32) -----------
__global__ void __launch_bounds__(1024, 8) k_aggb2(const unsigned short* __restrict__ g16b,
                                                   const unsigned* __restrict__ packed,
                                                   const int* __restrict__ gcursor,
                                                   const float* __restrict__ dis,
                                                   const float* __restrict__ bias,
                                                   float* __restrict__ out,
                                                   int N) {
    __shared__ float acc[BK_NODES * ACCW];     // 67 KB
    int t = threadIdx.x;
    int b = blockIdx.x;
    int node0 = b << BK_SHIFT;
    for (int i = t; i < BK_NODES * ACCW; i += 1024) acc[i] = 0.f;
    __syncthreads();

    int e0 = b * CAP;
    int count = gcursor[b] - e0;
    int lane = t & 63;
    int wv = t >> 6;
    int sub = lane >> 3;
    int fl = lane & 7;
    for (int base = wv << 6; base < count; base += 1024) {
        int idx = base + lane;
        unsigned pe = (idx < count) ? packed[e0 + idx] : 0xFFFFFFFFu;
#pragma unroll
        for (int k = 0; k < 8; ++k) {
            unsigned p = __shfl(pe, k * 8 + sub);
            if (p != 0xFFFFFFFFu) {
                int srcn = (int)(p & 0x1FFFFu);
                int dl = (int)(p >> 17);
                uint4 u = *((const uint4*)(g16b + ((size_t)srcn << 6)) + fl);
                float* ap = &acc[dl * ACCW + fl * 8];
                atomicAdd(ap + 0, blo(u.x)); atomicAdd(ap + 1, bhi(u.x));
                atomicAdd(ap + 2, blo(u.y)); atomicAdd(ap + 3, bhi(u.y));
                atomicAdd(ap + 4, blo(u.z)); atomicAdd(ap + 5, bhi(u.z));
                atomicAdd(ap + 6, blo(u.w)); atomicAdd(ap + 7, bhi(u.w));
            }
        }
    }
    __syncthreads();

    {
        int row = t >> 2;
        int fg = (t & 3) << 4;
        int node = node0 + row;
        if (node < N) {
            float s = dis[node];
            const uint4* sp = (const uint4*)(g16b + ((size_t)node << 6)) + ((t & 3) << 1);
            uint4 u0 = sp[0], u1 = sp[1];
            float sv[16];
            sv[0] = blo(u0.x); sv[1] = bhi(u0.x); sv[2] = blo(u0.y); sv[3] = bhi(u0.y);
            sv[4] = blo(u0.z); sv[5] = bhi(u0.z); sv[6] = blo(u0.w); sv[7] = bhi(u0.w);
            sv[8] = blo(u1.x); sv[9] = bhi(u1.x); sv[10] = blo(u1.y); sv[11] = bhi(u1.y);
            sv[12] = blo(u1.z); sv[13] = bhi(u1.z); sv[14] = blo(u1.w); sv[15] = bhi(u1.w);
            const float* ap = &acc[row * ACCW + fg];
            float o[16];
#pragma unroll
            for (int j = 0; j < 16; ++j)
                o[j] = fmaf(s, ap[j] + sv[j], bias[fg + j]);
            float4* op = (float4*)(out + ((size_t)node << 6) + fg);
            op[0] = (float4){o[0], o[1], o[2], o[3]};
            op[1] = (float4){o[4], o[5], o[6], o[7]};
            op[2] = (float4){o[8], o[9], o[10], o[11]};
            op[3] = (float4){o[12], o[13], o[14], o[15]};
        }
    }
}

extern "C" void kernel_launch(void* const* d_in, const int* in_sizes, int n_in,
                              void* d_out, int out_size, void* d_ws, size_t ws_size,
                              hipStream_t stream) {
    const float* x  = (const float*)d_in[0];
    const int*   ei = (const int*)d_in[1];
    const float* W1 = (const float*)d_in[2];
    const float* b1 = (const float*)d_in[3];
    const float* W2 = (const float*)d_in[4];
    const float* b2 = (const float*)d_in[5];
    float* out = (float*)d_out;

    const int N = in_sizes[0] / 64;
    const int E = in_sizes[1] / 2;
    const int NB = (N + BK_NODES - 1) >> BK_SHIFT;
    const int nstrips = (N + 15) >> 4;
    const int* src = ei;
    const int* dst = ei + E;

    char* ws = (char*)d_ws;
    size_t off = 0;
    auto alloc = [&](size_t bytes) -> void* {
        void* p = ws + off;
        off = (off + bytes + 255) & ~(size_t)255;
        return p;
    };
    int*            gcursor = (int*)alloc((size_t)NB * 4);
    float*          dis     = (float*)alloc((size_t)N * 4);
    unsigned*       packed  = (unsigned*)alloc((size_t)NB * CAP * 4);
    unsigned short* g16     = (unsigned short*)alloc((size_t)N * 64 * 2);
    unsigned short* g16b    = (unsigned short*)alloc((size_t)N * 64 * 2);
    (void)ws_size;

    k_init<<<1, 512, 0, stream>>>(gcursor, NB);
    k_bscatter<<<(E + EPB - 1) / EPB, 256, 0, stream>>>(src, dst, gcursor, packed, E, NB);
    k_count<<<NB, 256, 0, stream>>>(packed, gcursor, dis, N);

    k_gemm_mfma<<<782, 256, 0, stream>>>(x, W1, dis, g16, N, nstrips);
    k_aggb1<<<NB, 1024, 0, stream>>>(g16, packed, gcursor, dis, b1, W2, g16b, N);
    k_aggb2<<<NB, 1024, 0, stream>>>(g16b, packed, gcursor, dis, b2, out, N);
}